// Round 7
// baseline (36.208 us; speedup 1.0000x reference)
//
#include <hip/hip_runtime.h>
#include <math.h>

#define BLK  256
#define NPTS 4096
#define NB   8
#define QPB  512            // queries (points) per block
#define RCH  512            // refs (gts) per chunk
#define QC   (NPTS / QPB)   // 8 query chunks
#define RS   (NPTS / RCH)   // 8 ref chunks
#define SP   8

typedef _Float16 h8 __attribute__((ext_vector_type(8)));
typedef float    f4 __attribute__((ext_vector_type(4)));

__device__ __forceinline__ void split2(float v, _Float16& h, _Float16& l) {
    h = (_Float16)v;
    l = (_Float16)(v - (float)h);
}

// A-side (points): slots [ah(5), ah(5), al(5), al(5), 0 x12] with
// a = [-2px, -2py, -2pz, pn, 1]. kg selects slots kg*8..kg*8+7.
__device__ __forceinline__ h8 make_afrag(float x, float y, float z, int kg) {
    const float m2x = -2.f * x, m2y = -2.f * y, m2z = -2.f * z;
    const float pn = fmaf(x, x, fmaf(y, y, z * z));
    _Float16 xh, xl, yh, yl, zh, zl, ph, pl;
    split2(m2x, xh, xl); split2(m2y, yh, yl); split2(m2z, zh, zl); split2(pn, ph, pl);
    const _Float16 one = (_Float16)1.f, zr = (_Float16)0.f;
    h8 f;
    if (kg == 0)      f = (h8){xh, yh, zh, ph, one, xh, yh, zh};
    else if (kg == 1) f = (h8){ph, one, xl, yl, zl, pl, zr, xl};
    else if (kg == 2) f = (h8){yl, zl, pl, zr, zr, zr, zr, zr};
    else              f = (h8){zr, zr, zr, zr, zr, zr, zr, zr};
    return f;
}

// B-side (gts): slots [bh(5), bl(5), bh(5), bl(5), 0 x12] with
// b = [gx, gy, gz, 1, gn]. Pairs with A so sum_k a_k*b_k = pn + gn - 2 p.g exact.
__device__ __forceinline__ h8 make_bfrag(float x, float y, float z, int kg) {
    const float gn = fmaf(x, x, fmaf(y, y, z * z));
    _Float16 xh, xl, yh, yl, zh, zl, nh, nl;
    split2(x, xh, xl); split2(y, yh, yl); split2(z, zh, zl); split2(gn, nh, nl);
    const _Float16 one = (_Float16)1.f, zr = (_Float16)0.f;
    h8 f;
    if (kg == 0)      f = (h8){xh, yh, zh, one, nh, xl, yl, zl};
    else if (kg == 1) f = (h8){zr, nl, xh, yh, zh, one, nh, xl};
    else if (kg == 2) f = (h8){yl, zl, zr, nl, zr, zr, zr, zr};
    else              f = (h8){zr, zr, zr, zr, zr, zr, zr, zr};
    return f;
}

// Stage 1: one block per (batch, q-chunk, r-chunk). 512x512 tile of the
// distance matrix via 16x16x32 f16 MFMA (hi/lo split => fp32-exact d).
// Each wave owns 8 q-tiles (A-frags in regs), streams 32 r-tiles' B-frags
// from LDS (pre-arranged [rt][lane] => conflict-free ds_read_b128).
// Min-reduces the SAME d both ways: qacc (over refs) + rbuf (over queries).
__global__ __launch_bounds__(BLK, 2) void chamfer_mfma(
    const float* __restrict__ P, const float* __restrict__ G,
    float* __restrict__ qpart,   // [NB][RS][NPTS]  min over ref-chunk, per point
    float* __restrict__ rpart)   // [NB][QC][NPTS]  min over query-chunk, per gt
{
    __shared__ h8    Bfr[(RCH / 16) * 64];   // 32 KB
    __shared__ float rbuf[16 * RCH];         // 32 KB  [wave*4+kg][ref]

    const int qc = blockIdx.x / RS;
    const int rc = blockIdx.x % RS;
    const int b  = blockIdx.y;
    const int tid  = threadIdx.x;
    const int wave = tid >> 6;
    const int lane = tid & 63;
    const int lrow = lane & 15;
    const int kg   = lane >> 4;

    const float* __restrict__ Pb = P + (size_t)b * NPTS * 3;
    const float* __restrict__ Gb = G + (size_t)b * NPTS * 3;

    // stage B-frags
    for (int e = tid; e < (RCH / 16) * 64; e += BLK) {
        const int el = e & 63;
        const int rg = rc * RCH + (e >> 6) * 16 + (el & 15);
        Bfr[e] = make_bfrag(Gb[3 * rg], Gb[3 * rg + 1], Gb[3 * rg + 2], el >> 4);
    }

    // A-frags straight to registers
    h8 afr[8];
    f4 qacc[8];
#pragma unroll
    for (int t = 0; t < 8; ++t) {
        const int qg = qc * QPB + (wave * 8 + t) * 16 + lrow;
        afr[t] = make_afrag(Pb[3 * qg], Pb[3 * qg + 1], Pb[3 * qg + 2], kg);
        qacc[t] = (f4){3.4e38f, 3.4e38f, 3.4e38f, 3.4e38f};
    }

    __syncthreads();

    for (int rt = 0; rt < RCH / 16; ++rt) {
        const h8 bfr = Bfr[rt * 64 + lane];
        float rmn = 3.4e38f;
#pragma unroll
        for (int t = 0; t < 8; ++t) {
            f4 d = __builtin_amdgcn_mfma_f32_16x16x32_f16(
                       afr[t], bfr, (f4){0.f, 0.f, 0.f, 0.f}, 0, 0, 0);
            qacc[t][0] = fminf(qacc[t][0], d[0]);
            qacc[t][1] = fminf(qacc[t][1], d[1]);
            qacc[t][2] = fminf(qacc[t][2], d[2]);
            qacc[t][3] = fminf(qacc[t][3], d[3]);
            rmn = fminf(rmn, fminf(fminf(d[0], d[1]), fminf(d[2], d[3])));
        }
        rbuf[(wave * 4 + kg) * RCH + rt * 16 + lrow] = rmn;
    }

    // q-direction: min across the 16 col-slots (refs), store per-point partial
    float* qout = qpart + ((size_t)b * RS + rc) * NPTS + qc * QPB;
#pragma unroll
    for (int t = 0; t < 8; ++t) {
#pragma unroll
        for (int j = 0; j < 4; ++j) {
            float v = qacc[t][j];
            v = fminf(v, __shfl_xor(v, 1, 64));
            v = fminf(v, __shfl_xor(v, 2, 64));
            v = fminf(v, __shfl_xor(v, 4, 64));
            v = fminf(v, __shfl_xor(v, 8, 64));
            if (lrow == 0) qout[(wave * 8 + t) * 16 + kg * 4 + j] = v;
        }
    }

    // r-direction: combine the 16 row-group partials, store per-gt partial
    __syncthreads();
    float* rout = rpart + ((size_t)b * QC + qc) * NPTS + rc * RCH;
    for (int rr = tid; rr < RCH; rr += BLK) {
        float v = rbuf[rr];
#pragma unroll
        for (int g = 1; g < 16; ++g) v = fminf(v, rbuf[g * RCH + rr]);
        rout[rr] = v;
    }
}

// Stage 2: min-combine the 8 chunk-partials per element, clamp, block-sum.
// Same layout for both paths: [b][chunk][NPTS].
__global__ __launch_bounds__(BLK) void chamfer_combine(
    const float* __restrict__ qpart, const float* __restrict__ rpart,
    float* __restrict__ sums)   // [2][NB][SP]
{
    const int path = blockIdx.x / (NB * SP);
    const int b    = (blockIdx.x / SP) % NB;
    const int sp   = blockIdx.x % SP;
    const float* __restrict__ base = (path ? rpart : qpart) + (size_t)b * 8 * NPTS;

    float s = 0.f;
#pragma unroll
    for (int i = 0; i < NPTS / SP / BLK; ++i) {   // 2
        const int q = sp * (NPTS / SP) + i * BLK + threadIdx.x;
        float mn = base[q];
#pragma unroll
        for (int c = 1; c < 8; ++c) mn = fminf(mn, base[(size_t)c * NPTS + q]);
        s += fmaxf(mn, 0.f);
    }

    __shared__ float red[BLK];
    red[threadIdx.x] = s;
    __syncthreads();
    if (threadIdx.x < 128) red[threadIdx.x] += red[threadIdx.x + 128];
    __syncthreads();
    if (threadIdx.x < 64) {
        float v = red[threadIdx.x] + red[threadIdx.x + 64];
#pragma unroll
        for (int off = 32; off > 0; off >>= 1) v += __shfl_down(v, off, 64);
        if (threadIdx.x == 0) sums[blockIdx.x] = v;
    }
}

// Stage 3: 16 x sqrt(mean), then the 3 scalar outputs.
__global__ __launch_bounds__(64) void chamfer_final(
    const float* __restrict__ sums, float* __restrict__ out)
{
    __shared__ float r16[16];
    if (threadIdx.x < 16) {
        float s = 0.f;
#pragma unroll
        for (int sp = 0; sp < SP; ++sp) s += sums[threadIdx.x * SP + sp];
        r16[threadIdx.x] = sqrtf(s / (float)NPTS);
    }
    __syncthreads();
    if (threadIdx.x == 0) {
        float p2g = 0.f, g2p = 0.f;
#pragma unroll
        for (int bb = 0; bb < NB; ++bb) { p2g += r16[bb]; g2p += r16[NB + bb]; }
        p2g *= (1.0f / NB);
        g2p *= (1.0f / NB);
        out[0] = 0.5f * (p2g + g2p);
        out[1] = p2g;
        out[2] = g2p;
    }
}

extern "C" void kernel_launch(void* const* d_in, const int* in_sizes, int n_in,
                              void* d_out, int out_size, void* d_ws, size_t ws_size,
                              hipStream_t stream) {
    const float* points = (const float*)d_in[0];
    const float* gts    = (const float*)d_in[1];
    float* out = (float*)d_out;

    float* qpart = (float*)d_ws;                         // NB*RS*NPTS = 1 MB
    float* rpart = qpart + (size_t)NB * RS * NPTS;       // NB*QC*NPTS = 1 MB
    float* sums  = rpart + (size_t)NB * QC * NPTS;       // 2*NB*SP floats

    dim3 grid1(QC * RS, NB);                             // 512 blocks, 2/CU
    chamfer_mfma<<<grid1, BLK, 0, stream>>>(points, gts, qpart, rpart);

    chamfer_combine<<<dim3(2 * NB * SP), BLK, 0, stream>>>(qpart, rpart, sums);

    chamfer_final<<<dim3(1), 64, 0, stream>>>(sums, out);
}

// Round 8
// 33.923 us; speedup vs baseline: 1.0674x; 1.0674x over previous
//
#include <hip/hip_runtime.h>
#include <math.h>

#define BLK  256
#define NPTS 4096
#define B    8
#define SP   8     // stage-2 split per (dir,b)

#define FOREACH_Q(OP) OP(0) OP(1) OP(2) OP(3) OP(4) OP(5) OP(6) OP(7)

// Stage 1: one block per (dir, batch, qchunk, refchunk). grid.x = 2*RS.
// 256 threads x 8 queries = 2048 queries/block (qchunks=2).
// Refs split RS=32 ways -> 128 refs staged in 2KB LDS as (x,y,z,||g||^2).
// 1024 blocks = 4 blocks/CU = 4 waves/SIMD: hides ds_read + waitcnt stalls.
// Inner window: 4 broadcast ds_read_b128 + 8q x (12 fma + ~3 min).
template<int RS>
__global__ __launch_bounds__(BLK, 4) void chamfer_partial(
    const float* __restrict__ P,
    const float* __restrict__ G,
    float* __restrict__ partial)   // [2][B][RS][NPTS] partial mins (pn deferred)
{
    constexpr int RCH = NPTS / RS;
    __shared__ float4 lds[RCH];

    const int dir = blockIdx.z;
    const int b   = blockIdx.y;
    const int qc  = blockIdx.x / RS;
    const int r   = blockIdx.x % RS;

    const float* __restrict__ Qb = (dir ? G : P) + (size_t)b * NPTS * 3;
    const float* __restrict__ Rb = (dir ? P : G) + (size_t)b * NPTS * 3;

    const int j0 = r * RCH;
    for (int j = threadIdx.x; j < RCH; j += BLK) {
        float x = Rb[3 * (j0 + j) + 0];
        float y = Rb[3 * (j0 + j) + 1];
        float z = Rb[3 * (j0 + j) + 2];
        lds[j] = make_float4(x, y, z, fmaf(x, x, fmaf(y, y, z * z)));
    }

    const int qbase = qc * (BLK * 8);

#define DECLQ(i) float m2x##i, m2y##i, m2z##i, acc##i;
    FOREACH_Q(DECLQ)
#undef DECLQ

#define LOADQ(i) { const int qi = qbase + (i) * BLK + threadIdx.x;           \
        m2x##i = -2.f * Qb[3 * qi + 0];                                      \
        m2y##i = -2.f * Qb[3 * qi + 1];                                      \
        m2z##i = -2.f * Qb[3 * qi + 2];                                      \
        acc##i = 3.4e38f; }
    FOREACH_Q(LOADQ)
#undef LOADQ

    __syncthreads();

#pragma unroll 2
    for (int j = 0; j < RCH; j += 4) {
        const float4 g0 = lds[j + 0];
        const float4 g1 = lds[j + 1];
        const float4 g2 = lds[j + 2];
        const float4 g3 = lds[j + 3];
#define EVALQ(i) {                                                           \
        float t0 = fmaf(m2x##i, g0.x, g0.w);                                 \
        t0 = fmaf(m2y##i, g0.y, t0);                                         \
        t0 = fmaf(m2z##i, g0.z, t0);                                         \
        float t1 = fmaf(m2x##i, g1.x, g1.w);                                 \
        t1 = fmaf(m2y##i, g1.y, t1);                                         \
        t1 = fmaf(m2z##i, g1.z, t1);                                         \
        float t2 = fmaf(m2x##i, g2.x, g2.w);                                 \
        t2 = fmaf(m2y##i, g2.y, t2);                                         \
        t2 = fmaf(m2z##i, g2.z, t2);                                         \
        float t3 = fmaf(m2x##i, g3.x, g3.w);                                 \
        t3 = fmaf(m2y##i, g3.y, t3);                                         \
        t3 = fmaf(m2z##i, g3.z, t3);                                         \
        acc##i = fminf(fminf(t0, t1), fminf(fminf(t2, t3), acc##i)); }
        FOREACH_Q(EVALQ)
#undef EVALQ
    }

    float* out_base = partial + (((size_t)dir * B + b) * RS + r) * NPTS;
#define STOREQ(i) out_base[qbase + (i) * BLK + threadIdx.x] = acc##i;
    FOREACH_Q(STOREQ)
#undef STOREQ
}

// Stage 2: grid = 2*B*SP blocks; min-combine RS partials per query,
// add pn, clamp, block-sum.
template<int RS>
__global__ __launch_bounds__(BLK) void chamfer_reduce(
    const float* __restrict__ P, const float* __restrict__ G,
    const float* __restrict__ partial, float* __restrict__ sums)
{
    const int dirb = blockIdx.x / SP;
    const int sp   = blockIdx.x % SP;
    const int dir  = dirb >> 3;
    const int b    = dirb & 7;
    const float* __restrict__ Qb   = (dir ? G : P) + (size_t)b * NPTS * 3;
    const float* __restrict__ base = partial + (size_t)dirb * RS * NPTS;

    float sum = 0.f;
#pragma unroll
    for (int i = 0; i < NPTS / SP / BLK; ++i) {
        const int q = sp * (NPTS / SP) + i * BLK + threadIdx.x;
        float mn = base[q];
#pragma unroll
        for (int rr = 1; rr < RS; ++rr) mn = fminf(mn, base[(size_t)rr * NPTS + q]);
        const float x = Qb[3 * q + 0];
        const float y = Qb[3 * q + 1];
        const float z = Qb[3 * q + 2];
        sum += fmaxf(fmaf(x, x, fmaf(y, y, z * z)) + mn, 0.f);
    }

    __shared__ float red[BLK];
    red[threadIdx.x] = sum;
    __syncthreads();
    if (threadIdx.x < 128) red[threadIdx.x] += red[threadIdx.x + 128];
    __syncthreads();
    if (threadIdx.x < 64) {
        float v = red[threadIdx.x] + red[threadIdx.x + 64];
#pragma unroll
        for (int off = 32; off > 0; off >>= 1) v += __shfl_down(v, off, 64);
        if (threadIdx.x == 0) sums[blockIdx.x] = v;   // [dirb][sp]
    }
}

// Stage 3: 16 x sqrt(mean), then the 3 scalar outputs.
__global__ __launch_bounds__(64) void chamfer_final(
    const float* __restrict__ sums, float* __restrict__ out)
{
    __shared__ float r16[16];
    if (threadIdx.x < 16) {
        float s = 0.f;
#pragma unroll
        for (int sp = 0; sp < SP; ++sp) s += sums[threadIdx.x * SP + sp];
        r16[threadIdx.x] = sqrtf(s / (float)NPTS);
    }
    __syncthreads();
    if (threadIdx.x == 0) {
        float p2g = 0.f, g2p = 0.f;
#pragma unroll
        for (int bb = 0; bb < B; ++bb) { p2g += r16[bb]; g2p += r16[B + bb]; }
        p2g *= (1.0f / B);
        g2p *= (1.0f / B);
        out[0] = 0.5f * (p2g + g2p);
        out[1] = p2g;
        out[2] = g2p;
    }
}

extern "C" void kernel_launch(void* const* d_in, const int* in_sizes, int n_in,
                              void* d_out, int out_size, void* d_ws, size_t ws_size,
                              hipStream_t stream) {
    const float* points = (const float*)d_in[0];
    const float* gts    = (const float*)d_in[1];
    float* out = (float*)d_out;
    float* partial = (float*)d_ws;

    const size_t need32 = (size_t)2 * B * 32 * NPTS * 4 + 1024;
    const bool use32 = (ws_size >= need32);

    if (use32) {
        float* sums = partial + (size_t)2 * B * 32 * NPTS;
        dim3 grid1(2 * 32, B, 2);   // 1024 blocks -> 4 blocks/CU, 4 waves/SIMD
        chamfer_partial<32><<<grid1, BLK, 0, stream>>>(points, gts, partial);
        chamfer_reduce<32><<<dim3(2 * B * SP), BLK, 0, stream>>>(points, gts, partial, sums);
        chamfer_final<<<dim3(1), 64, 0, stream>>>(sums, out);
    } else {
        float* sums = partial + (size_t)2 * B * 16 * NPTS;
        dim3 grid1(2 * 16, B, 2);   // 512 blocks fallback
        chamfer_partial<16><<<grid1, BLK, 0, stream>>>(points, gts, partial);
        chamfer_reduce<16><<<dim3(2 * B * SP), BLK, 0, stream>>>(points, gts, partial, sums);
        chamfer_final<<<dim3(1), 64, 0, stream>>>(sums, out);
    }
}

// Round 9
// 21.001 us; speedup vs baseline: 1.7241x; 1.6153x over previous
//
#include <hip/hip_runtime.h>
#include <math.h>

#define NPTS 4096
#define NB   8
#define QCB  512          // queries per block (16 waves x 32 rows)
#define RCB  1024         // refs per block (32 tiles x 32)
#define NQC  (NPTS / QCB) // 8
#define NRC  (NPTS / RCB) // 4

typedef _Float16 h8   __attribute__((ext_vector_type(8)));
typedef float    f32x16 __attribute__((ext_vector_type(16)));

__device__ __forceinline__ void split2(float v, _Float16& h, _Float16& l) {
    h = (_Float16)v;
    l = (_Float16)(v - (float)h);
}

// d = pn + gn - 2 p.g embedded in K=16 f16 dot product, hi/lo split:
// A slots: k0-4 = ah[m2x,m2y,m2z,pn,1], k5-7 = al[m2x,m2y,m2z],
//          k8 = pn_lo, k9 = 0, k10-14 = ah again, k15 = 0
// B slots: k0-4 = bh[gx,gy,gz,1,gn], k5-7 = bh[gx,gy,gz],
//          k8 = 1, k9 = gn_hi, k10-14 = bl[gx,gy,gz,0,gn_lo]... (see pairing)
// Products: hh (k0-4), lo_a*hi_b (k5-8), hi_a*lo_b (k10-14). Error ~1e-6.
__global__ __launch_bounds__(1024, 1) void chamfer_mfma32(
    const float* __restrict__ P, const float* __restrict__ G,
    float* __restrict__ qpart,   // [NB][NRC][NPTS] per-point min over ref-chunk
    float* __restrict__ rpart)   // [NB][NQC][NPTS] per-gt min over query-chunk
{
    __shared__ __align__(16) unsigned char smem[77824];
    h8*   Bfr  = (h8*)smem;                    // [0, 32768): 32 tiles x 64 entries
    int*  rbuf = (int*)(smem + 73728);         // [73728, 77824): 1024 col-min ints
    float* qbufall = (float*)smem;             // [0, 73728): aliased, phase 3 only

    const int b    = blockIdx.y;
    const int qc   = blockIdx.x >> 2;   // 0..7
    const int rc   = blockIdx.x & 3;    // 0..3
    const int tid  = threadIdx.x;
    const int w    = tid >> 6;
    const int lane = tid & 63;
    const int col  = lane & 31;
    const int kg   = lane >> 5;

    const float* __restrict__ Pb = P + (size_t)b * NPTS * 3;
    const float* __restrict__ Gb = G + (size_t)b * NPTS * 3;

    const _Float16 one = (_Float16)1.f, zr = (_Float16)0.f;

    // ---- phase 0: stage B-frags (2048 entries, 2/thread) + init rbuf
    rbuf[tid] = 0x7f7fffff;   // FLT_MAX bits (values are clamped >= 0)
    for (int e = tid; e < 32 * 64; e += 1024) {
        const int el   = e & 63;
        const int ecol = el & 31, ekg = el >> 5;
        const int ref  = rc * RCB + (e >> 6) * 32 + ecol;
        const float gx = Gb[3 * ref], gy = Gb[3 * ref + 1], gz = Gb[3 * ref + 2];
        const float gn = fmaf(gx, gx, fmaf(gy, gy, gz * gz));
        _Float16 xh, xl, yh, yl, zh, zl, nh, nl;
        split2(gx, xh, xl); split2(gy, yh, yl); split2(gz, zh, zl); split2(gn, nh, nl);
        Bfr[e] = ekg ? (h8){one, nh, xl, yl, zl, zr, nl, zr}
                     : (h8){xh, yh, zh, one, nh, xh, yh, zh};
    }

    // ---- A-frag (per lane, held in registers)
    {
    }
    const int q0 = qc * QCB + w * 32 + col;
    const float px = Pb[3 * q0], py = Pb[3 * q0 + 1], pz = Pb[3 * q0 + 2];
    const float m2x = -2.f * px, m2y = -2.f * py, m2z = -2.f * pz;
    const float pn = fmaf(px, px, fmaf(py, py, pz * pz));
    _Float16 axh, axl, ayh, ayl, azh, azl, aph, apl;
    split2(m2x, axh, axl); split2(m2y, ayh, ayl); split2(m2z, azh, azl); split2(pn, aph, apl);
    const h8 afr = kg ? (h8){apl, zr, axh, ayh, azh, aph, one, zr}
                      : (h8){axh, ayh, azh, aph, one, axl, ayl, azl};

    f32x16 qacc;
#pragma unroll
    for (int j = 0; j < 16; ++j) qacc[j] = 3.4e38f;

    __syncthreads();

    // ---- phase 1: 32 MFMAs; row-min into qacc regs, col-min -> LDS atomicMin
    const f32x16 cz = (f32x16){0.f,0.f,0.f,0.f,0.f,0.f,0.f,0.f,
                               0.f,0.f,0.f,0.f,0.f,0.f,0.f,0.f};
#pragma unroll 4
    for (int rt = 0; rt < 32; ++rt) {
        const h8 bfr = Bfr[rt * 64 + lane];
        f32x16 d = __builtin_amdgcn_mfma_f32_32x32x16_f16(afr, bfr, cz, 0, 0, 0);
#pragma unroll
        for (int j = 0; j < 16; ++j) qacc[j] = fminf(qacc[j], d[j]);
        // col-min over this lane's 16 rows (the atomic merges the two kg halves)
        float t0 = fminf(fminf(d[0],  d[1]),  d[2]);
        float t1 = fminf(fminf(d[3],  d[4]),  d[5]);
        float t2 = fminf(fminf(d[6],  d[7]),  d[8]);
        float t3 = fminf(fminf(d[9],  d[10]), d[11]);
        float t4 = fminf(fminf(d[12], d[13]), d[14]);
        float v  = fminf(fminf(fminf(t0, t1), t2), fminf(fminf(t3, t4), d[15]));
        v = fmaxf(v, 0.f);
        atomicMin(&rbuf[rt * 32 + col], __float_as_int(v));
    }

    // ---- phase 2: drain rbuf -> rpart
    __syncthreads();
    rpart[((size_t)b * NQC + qc) * NPTS + rc * RCB + tid] = __int_as_float(rbuf[tid]);
    __syncthreads();   // Bfr + rbuf dead; qbuf may alias

    // ---- phase 3: qacc row-min via padded LDS transpose (per wave region)
    float* qw = qbufall + w * 1152;           // 32 rows x 36 floats = 4608 B
#pragma unroll
    for (int j = 0; j < 16; ++j) {
        const int row = (j & 3) + 8 * (j >> 2) + 4 * kg;
        qw[row * 36 + col] = qacc[j];
    }
    __syncthreads();
    const float4* qr = (const float4*)(qw + col * 36);
    float4 v0 = qr[0], v1 = qr[1], v2 = qr[2], v3 = qr[3];
    float4 v4 = qr[4], v5 = qr[5], v6 = qr[6], v7 = qr[7];
    float4 m01 = make_float4(fminf(v0.x,v1.x), fminf(v0.y,v1.y), fminf(v0.z,v1.z), fminf(v0.w,v1.w));
    float4 m23 = make_float4(fminf(v2.x,v3.x), fminf(v2.y,v3.y), fminf(v2.z,v3.z), fminf(v2.w,v3.w));
    float4 m45 = make_float4(fminf(v4.x,v5.x), fminf(v4.y,v5.y), fminf(v4.z,v5.z), fminf(v4.w,v5.w));
    float4 m67 = make_float4(fminf(v6.x,v7.x), fminf(v6.y,v7.y), fminf(v6.z,v7.z), fminf(v6.w,v7.w));
    float4 ma = make_float4(fminf(m01.x,m23.x), fminf(m01.y,m23.y), fminf(m01.z,m23.z), fminf(m01.w,m23.w));
    float4 mb = make_float4(fminf(m45.x,m67.x), fminf(m45.y,m67.y), fminf(m45.z,m67.z), fminf(m45.w,m67.w));
    const float rowmin = fminf(fminf(fminf(ma.x, ma.y), fminf(ma.z, ma.w)),
                               fminf(fminf(mb.x, mb.y), fminf(mb.z, mb.w)));
    if (lane < 32)
        qpart[((size_t)b * NRC + rc) * NPTS + qc * QCB + w * 32 + col] = rowmin;
}

// Stage 2: 16 blocks: per (path, b) min-combine chunk partials, clamp, sum,
// sqrt(mean) -> r16[path*8 + b].
__global__ __launch_bounds__(256) void chamfer_reduce2(
    const float* __restrict__ qpart, const float* __restrict__ rpart,
    float* __restrict__ r16)
{
    const int path = blockIdx.x >> 3;
    const int b    = blockIdx.x & 7;
    float sum = 0.f;
    if (path == 0) {
        const float* __restrict__ base = qpart + (size_t)b * NRC * NPTS;
        for (int i = 0; i < NPTS / 256; ++i) {
            const int qq = i * 256 + threadIdx.x;
            float mn = base[qq];
#pragma unroll
            for (int c = 1; c < NRC; ++c) mn = fminf(mn, base[(size_t)c * NPTS + qq]);
            sum += fmaxf(mn, 0.f);
        }
    } else {
        const float* __restrict__ base = rpart + (size_t)b * NQC * NPTS;
        for (int i = 0; i < NPTS / 256; ++i) {
            const int qq = i * 256 + threadIdx.x;
            float mn = base[qq];
#pragma unroll
            for (int c = 1; c < NQC; ++c) mn = fminf(mn, base[(size_t)c * NPTS + qq]);
            sum += fmaxf(mn, 0.f);
        }
    }
    __shared__ float red[256];
    red[threadIdx.x] = sum;
    __syncthreads();
    if (threadIdx.x < 128) red[threadIdx.x] += red[threadIdx.x + 128];
    __syncthreads();
    if (threadIdx.x < 64) {
        float v = red[threadIdx.x] + red[threadIdx.x + 64];
#pragma unroll
        for (int off = 32; off > 0; off >>= 1) v += __shfl_down(v, off, 64);
        if (threadIdx.x == 0) r16[blockIdx.x] = sqrtf(v / (float)NPTS);
    }
}

// Stage 3: combine 16 per-(path,batch) values into the 3 scalar outputs.
__global__ __launch_bounds__(64) void chamfer_final(
    const float* __restrict__ r16, float* __restrict__ out)
{
    if (threadIdx.x == 0) {
        float p2g = 0.f, g2p = 0.f;
#pragma unroll
        for (int bb = 0; bb < NB; ++bb) { p2g += r16[bb]; g2p += r16[NB + bb]; }
        p2g *= (1.0f / NB);
        g2p *= (1.0f / NB);
        out[0] = 0.5f * (p2g + g2p);
        out[1] = p2g;
        out[2] = g2p;
    }
}

extern "C" void kernel_launch(void* const* d_in, const int* in_sizes, int n_in,
                              void* d_out, int out_size, void* d_ws, size_t ws_size,
                              hipStream_t stream) {
    const float* points = (const float*)d_in[0];
    const float* gts    = (const float*)d_in[1];
    float* out = (float*)d_out;

    float* qpart = (float*)d_ws;                          // 8*4*4096 = 512 KB
    float* rpart = qpart + (size_t)NB * NRC * NPTS;       // 8*8*4096 = 1 MB
    float* r16   = rpart + (size_t)NB * NQC * NPTS;       // 16 floats

    dim3 grid1(NQC * NRC, NB);   // 32 x 8 = 256 blocks, 1024 thr, 1/CU
    chamfer_mfma32<<<grid1, 1024, 0, stream>>>(points, gts, qpart, rpart);

    chamfer_reduce2<<<dim3(16), 256, 0, stream>>>(qpart, rpart, r16);

    chamfer_final<<<dim3(1), 64, 0, stream>>>(r16, out);
}

// Round 10
// 20.514 us; speedup vs baseline: 1.7651x; 1.0238x over previous
//
#include <hip/hip_runtime.h>
#include <math.h>

#define NPTS 4096
#define NB   8
#define QCB  512          // queries per block (16 waves x 32 rows)
#define RCB  512          // refs per block (16 tiles x 32)
#define NQC  (NPTS / QCB) // 8
#define NRC  (NPTS / RCB) // 8
#define NRT  (RCB / 32)   // 16 ref tiles per block

typedef _Float16 h8     __attribute__((ext_vector_type(8)));
typedef float    f32x16 __attribute__((ext_vector_type(16)));

__device__ __forceinline__ void split2(float v, _Float16& h, _Float16& l) {
    h = (_Float16)v;
    l = (_Float16)(v - (float)h);
}

// d = pn + gn - 2 p.g embedded in a K=16 f16 dot product via hi/lo split
// (hh + lo_a*hi_b + hi_a*lo_b products; fp32-exact to ~1e-6, validated R9).
__global__ __launch_bounds__(1024, 2) void chamfer_mfma32(
    const float* __restrict__ P, const float* __restrict__ G,
    float* __restrict__ qpart,   // [NB][NRC][NPTS] per-point min over ref-chunk
    float* __restrict__ rpart,   // [NB][NQC][NPTS] per-gt min over query-chunk
    int* __restrict__ counter)
{
    __shared__ __align__(16) unsigned char smem[73728];
    h8*    Bfr  = (h8*)smem;                   // [0, 16384): 16 tiles x 64 entries
    int*   rbuf = (int*)(smem + 16384);        // [16384, 18432): 512 col-min ints
    float* qbufall = (float*)smem;             // aliased in phase 3 only

    const int b    = blockIdx.y;
    const int qc   = blockIdx.x >> 3;   // 0..7
    const int rc   = blockIdx.x & 7;    // 0..7
    const int tid  = threadIdx.x;
    const int w    = tid >> 6;
    const int lane = tid & 63;
    const int col  = lane & 31;
    const int kg   = lane >> 5;

    if (blockIdx.x == 0 && blockIdx.y == 0 && tid == 0) *counter = 0;

    const float* __restrict__ Pb = P + (size_t)b * NPTS * 3;
    const float* __restrict__ Gb = G + (size_t)b * NPTS * 3;

    const _Float16 one = (_Float16)1.f, zr = (_Float16)0.f;

    // ---- phase 0: stage B-frags (1024 entries) + init rbuf
    if (tid < 512) rbuf[tid] = 0x7f7fffff;     // FLT_MAX bits (values clamped >= 0)
    for (int e = tid; e < NRT * 64; e += 1024) {
        const int el   = e & 63;
        const int ecol = el & 31, ekg = el >> 5;
        const int ref  = rc * RCB + (e >> 6) * 32 + ecol;
        const float gx = Gb[3 * ref], gy = Gb[3 * ref + 1], gz = Gb[3 * ref + 2];
        const float gn = fmaf(gx, gx, fmaf(gy, gy, gz * gz));
        _Float16 xh, xl, yh, yl, zh, zl, nh, nl;
        split2(gx, xh, xl); split2(gy, yh, yl); split2(gz, zh, zl); split2(gn, nh, nl);
        Bfr[e] = ekg ? (h8){one, nh, xl, yl, zl, zr, nl, zr}
                     : (h8){xh, yh, zh, one, nh, xh, yh, zh};
    }

    // ---- A-frag (per lane, registers)
    const int q0 = qc * QCB + w * 32 + col;
    const float px = Pb[3 * q0], py = Pb[3 * q0 + 1], pz = Pb[3 * q0 + 2];
    const float m2x = -2.f * px, m2y = -2.f * py, m2z = -2.f * pz;
    const float pn = fmaf(px, px, fmaf(py, py, pz * pz));
    _Float16 axh, axl, ayh, ayl, azh, azl, aph, apl;
    split2(m2x, axh, axl); split2(m2y, ayh, ayl); split2(m2z, azh, azl); split2(pn, aph, apl);
    const h8 afr = kg ? (h8){apl, zr, axh, ayh, azh, aph, one, zr}
                      : (h8){axh, ayh, azh, aph, one, axl, ayl, azl};

    f32x16 qacc;
#pragma unroll
    for (int j = 0; j < 16; ++j) qacc[j] = 3.4e38f;

    __syncthreads();

    // ---- phase 1: NRT MFMAs; row-min into qacc regs, col-min -> LDS atomicMin
    const f32x16 cz = (f32x16){0.f,0.f,0.f,0.f,0.f,0.f,0.f,0.f,
                               0.f,0.f,0.f,0.f,0.f,0.f,0.f,0.f};
#pragma unroll 4
    for (int rt = 0; rt < NRT; ++rt) {
        const h8 bfr = Bfr[rt * 64 + lane];
        f32x16 d = __builtin_amdgcn_mfma_f32_32x32x16_f16(afr, bfr, cz, 0, 0, 0);
#pragma unroll
        for (int j = 0; j < 16; ++j) qacc[j] = fminf(qacc[j], d[j]);
        float t0 = fminf(fminf(d[0],  d[1]),  d[2]);
        float t1 = fminf(fminf(d[3],  d[4]),  d[5]);
        float t2 = fminf(fminf(d[6],  d[7]),  d[8]);
        float t3 = fminf(fminf(d[9],  d[10]), d[11]);
        float t4 = fminf(fminf(d[12], d[13]), d[14]);
        float v  = fminf(fminf(fminf(t0, t1), t2), fminf(fminf(t3, t4), d[15]));
        v = fmaxf(v, 0.f);
        atomicMin(&rbuf[rt * 32 + col], __float_as_int(v));
    }

    // ---- phase 2: drain rbuf -> rpart
    __syncthreads();
    if (tid < RCB)
        rpart[((size_t)b * NQC + qc) * NPTS + rc * RCB + tid] = __int_as_float(rbuf[tid]);
    __syncthreads();   // Bfr + rbuf dead; qbuf may alias

    // ---- phase 3: qacc row-min via padded LDS transpose (per-wave region)
    float* qw = qbufall + w * 1152;            // 32 rows x 36 floats
#pragma unroll
    for (int j = 0; j < 16; ++j) {
        const int row = (j & 3) + 8 * (j >> 2) + 4 * kg;
        qw[row * 36 + col] = qacc[j];
    }
    __syncthreads();
    if (lane < 32) {
        const float4* qr = (const float4*)(qw + col * 36);
        float4 v = qr[0];
#pragma unroll
        for (int k = 1; k < 8; ++k) {
            float4 u = qr[k];
            v.x = fminf(v.x, u.x); v.y = fminf(v.y, u.y);
            v.z = fminf(v.z, u.z); v.w = fminf(v.w, u.w);
        }
        const float rowmin = fminf(fminf(v.x, v.y), fminf(v.z, v.w));
        qpart[((size_t)b * NRC + rc) * NPTS + qc * QCB + w * 32 + col] = rowmin;
    }
}

// Stage 2 (+fused finalize): 64 blocks; block = (path, b, sp of 4).
// Min-combine the 8 chunk partials per element, clamp, block-sum -> sums[64].
// Last block (atomic counter) combines 64 sums -> 16 sqrt(mean) -> 3 outputs.
__global__ __launch_bounds__(256) void chamfer_reduce2(
    const float* __restrict__ qpart, const float* __restrict__ rpart,
    float* __restrict__ sums, int* __restrict__ counter,
    float* __restrict__ out)
{
    const int path = blockIdx.x >> 5;          // 0..1
    const int b    = (blockIdx.x >> 2) & 7;    // 0..7
    const int sp   = blockIdx.x & 3;           // 0..3
    const float* __restrict__ base = (path ? rpart : qpart) + (size_t)b * 8 * NPTS;

    float sum = 0.f;
#pragma unroll
    for (int i = 0; i < 4; ++i) {
        const int q = sp * 1024 + i * 256 + threadIdx.x;
        float mn = base[q];
#pragma unroll
        for (int c = 1; c < 8; ++c) mn = fminf(mn, base[(size_t)c * NPTS + q]);
        sum += fmaxf(mn, 0.f);
    }

    __shared__ float red[256];
    __shared__ int amLast;
    red[threadIdx.x] = sum;
    __syncthreads();
    if (threadIdx.x < 128) red[threadIdx.x] += red[threadIdx.x + 128];
    __syncthreads();
    if (threadIdx.x < 64) {
        float v = red[threadIdx.x] + red[threadIdx.x + 64];
#pragma unroll
        for (int off = 32; off > 0; off >>= 1) v += __shfl_down(v, off, 64);
        if (threadIdx.x == 0) {
            sums[blockIdx.x] = v;
            __threadfence();
            amLast = (atomicAdd(counter, 1) == 63);
        }
    }
    __syncthreads();

    if (amLast) {
        __shared__ float r16[16];
        if (threadIdx.x < 16) {
            float s = 0.f;
#pragma unroll
            for (int k = 0; k < 4; ++k)
                s += *(volatile const float*)&sums[threadIdx.x * 4 + k];
            r16[threadIdx.x] = sqrtf(s / (float)NPTS);
        }
        __syncthreads();
        if (threadIdx.x == 0) {
            float p2g = 0.f, g2p = 0.f;
#pragma unroll
            for (int bb = 0; bb < NB; ++bb) { p2g += r16[bb]; g2p += r16[NB + bb]; }
            p2g *= (1.0f / NB);
            g2p *= (1.0f / NB);
            out[0] = 0.5f * (p2g + g2p);
            out[1] = p2g;
            out[2] = g2p;
            *counter = 0;   // leave clean for next replay
        }
    }
}

extern "C" void kernel_launch(void* const* d_in, const int* in_sizes, int n_in,
                              void* d_out, int out_size, void* d_ws, size_t ws_size,
                              hipStream_t stream) {
    const float* points = (const float*)d_in[0];
    const float* gts    = (const float*)d_in[1];
    float* out = (float*)d_out;

    float* qpart = (float*)d_ws;                          // 8*8*4096 = 1 MB
    float* rpart = qpart + (size_t)NB * NRC * NPTS;       // 8*8*4096 = 1 MB
    float* sums  = rpart + (size_t)NB * NQC * NPTS;       // 64 floats
    int*   counter = (int*)(sums + 64);

    dim3 grid1(NQC * NRC, NB);   // 64 x 8 = 512 blocks, 1024 thr, 2/CU
    chamfer_mfma32<<<grid1, 1024, 0, stream>>>(points, gts, qpart, rpart, counter);

    chamfer_reduce2<<<dim3(64), 256, 0, stream>>>(qpart, rpart, sums, counter, out);
}